// Round 5
// baseline (15.464 us; speedup 1.0000x reference)
//
#include <hip/hip_runtime.h>
#include <cstdint>
#include <cstddef>

#define NWG 76
#define NHG 76
#define NAC 3
#define NCLS 80
#define NT 50
#define NTPAD 52
#define NBATCH 16
#define PLANE 5776                   // 76*76
#define CELLS_PER_B 17328            // 3*PLANE
#define CH_PER_A 85
#define CH_TOTAL 255
#define CHUNKS_PER_B 8664            // 17328/2, each chunk = 2 consecutive cells
#define BLK_X 34                     // ceil(8664/256)
#define NPART (BLK_X * NBATCH)       // 544
#define TOKEN 0x5A5A5A5Au

__device__ __forceinline__ float anchor_w(int n) { return n == 0 ? 10.f : n == 1 ? 16.f : 33.f; }
__device__ __forceinline__ float anchor_h(int n) { return n == 0 ? 13.f : n == 1 ? 30.f : 23.f; }

__device__ __forceinline__ float safe_bce_f(float p, float t) {
    float lp = (p > 0.0f) ? fmaxf(__logf(fmaxf(p, 1e-38f)), -100.0f) : -100.0f;
    float ln = (p < 1.0f) ? fmaxf(__logf(fmaxf(1.0f - p, 1e-38f)), -100.0f) : -100.0f;
    return -(t * lp + (1.0f - t) * ln);
}
__device__ __forceinline__ float bce_zero(float p) {   // safe_bce(p, 0)
    float ln = (p < 1.0f) ? fmaxf(__logf(fmaxf(1.0f - p, 1e-38f)), -100.0f) : -100.0f;
    return -ln;
}
__device__ __forceinline__ float softplus_f(float x) {
    return (x > 20.0f) ? x : log1pf(__expf(x));
}
// precise replication of reference iou_cc (rare paths only)
__device__ __forceinline__ float iou_cc_f(float x1, float y1, float w1, float h1,
                                          float x2, float y2, float w2, float h2) {
    float wu = fmaxf(x1 + w1 * 0.5f, x2 + w2 * 0.5f) - fminf(x1 - w1 * 0.5f, x2 - w2 * 0.5f);
    float hu = fmaxf(y1 + h1 * 0.5f, y2 + h2 * 0.5f) - fminf(y1 - h1 * 0.5f, y2 - h2 * 0.5f);
    float wc = w1 + w2 - wu;
    float hc = h1 + h2 - hu;
    float inter = (wc <= 0.0f || hc <= 0.0f) ? 0.0f : wc * hc;
    float uni = w1 * h1 + w2 * h2 - inter;
    return inter / uni;
}

// screen: covered <=> wc>0 && hc>0 && 3*inter > den  <=>  min3(wc,hc,3*wc*hc-den) > 0
__device__ __forceinline__ float eval1(float xh, float xl, float yh, float yl,
                                       float pwh, float4 E, float G, float B) {
    float wc = fminf(xh, E.x) - fmaxf(xl, E.y);
    float hc = fminf(yh, E.z) - fmaxf(yl, E.w);
    float t3 = fmaf(3.0f, wc * hc, -(pwh + G));
    return fmaxf(B, fminf(fminf(wc, hc), t3));
}

__global__ void __launch_bounds__(256) yolo_fused(const float* __restrict__ out,
                                                  const float* __restrict__ tgt,
                                                  unsigned long long* __restrict__ slots,
                                                  float* __restrict__ d_out) {
    __shared__ float4 corners[NTPAD];          // {gxh, gxl, gyh, gyl}; dummies kill inter
    __shared__ float4 sgwgh4[NTPAD / 4];       // per-target gw_*gh_ (SoA, broadcast b128)
    __shared__ float4 ax4[NT];                 // {tx, ty, tw, th}
    __shared__ int    skey[NT];                // cell key per target
    __shared__ int    scls[NT];                // class id per target
    __shared__ unsigned obm[16];               // obj-cell bitmap for this block's 512 cells
    __shared__ unsigned long long s_mm[2];     // ownership masks for target slots bx+34s
    __shared__ float partial[4];
    __shared__ int scnt;

    const int b = blockIdx.y, bx = blockIdx.x, tid = threadIdx.x;
    const float* outb = out + (size_t)b * CH_TOTAL * PLANE;
    const int blockStart = bx * 512;           // first CELL of this block

    // ---- issue this thread's 2-cell vector loads FIRST (latency hides under build) ----
    const int chunk = bx * 256 + tid;
    const bool validC = (chunk < CHUNKS_PER_B);
    const int cc = validC ? chunk : 0;
    const int cell0 = cc * 2;                  // 2 consecutive cells, same anchor, same row
    const int a = cell0 / PLANE;
    const int r0 = cell0 - a * PLANE;          // r0 % 2 == 0  -> 8B-aligned float2 loads
    const float* base = outb + (size_t)a * CH_PER_A * PLANE + r0;
    float2 X = *reinterpret_cast<const float2*>(base);
    float2 Y = *reinterpret_cast<const float2*>(base + PLANE);
    float2 W = *reinterpret_cast<const float2*>(base + 2 * PLANE);
    float2 H = *reinterpret_cast<const float2*>(base + 3 * PLANE);
    float2 C = *reinterpret_cast<const float2*>(base + 4 * PLANE);

    // ---- wave 0: build GT tables (tgt-only; NO out[] reads) ----
    if (tid < 64) {
        int t = tid;
        if (t < 16) obm[t] = 0u;

        float tb0 = 0.f, tb1 = 0.f, tb2 = 0.f, tb3 = 0.f, tb4 = 0.f;
        if (t < NT) {
            const float* p = tgt + (size_t)b * NT * 5 + t * 5;
            tb0 = p[0]; tb1 = p[1]; tb2 = p[2]; tb3 = p[3]; tb4 = p[4];
        }
        bool nz = (t < NT) && (tb1 != 0.0f);
        unsigned long long mask = __ballot(nz);
        unsigned long long inv = (~mask) & ((1ull << NT) - 1ull);
        int cnt = inv ? (int)__builtin_ctzll(inv) : NT;
        if (t == 0) scnt = cnt;

        int key = -1;
        if (t < cnt) {
            float gx = tb1 * (float)NWG, gy = tb2 * (float)NHG;
            float gw = tb3 * 608.0f,     gh = tb4 * 608.0f;
            float best = -1.0f; int bn = 0;
            #pragma unroll
            for (int n = 0; n < NAC; ++n) {
                float iou = iou_cc_f(0.f, 0.f, anchor_w(n), anchor_h(n), 0.f, 0.f, gw, gh);
                if (iou > best) { best = iou; bn = n; }
            }
            int gi = min(max((int)gx, 0), NWG - 1);
            int gj = min(max((int)gy, 0), NHG - 1);
            key = (bn * NHG + gj) * NWG + gi;  // == linear cell index within batch

            float xh = fmaf(0.5f, gw, gx), xl = fmaf(-0.5f, gw, gx);
            float yh = fmaf(0.5f, gh, gy), yl = fmaf(-0.5f, gh, gy);
            corners[t] = make_float4(xh, xl, yh, yl);
            ((float*)sgwgh4)[t] = (xh - xl) * (yh - yl);
            skey[t] = key;
            int rel = key - blockStart;
            if (rel >= 0 && rel < 512)
                atomicOr(&obm[rel >> 5], 1u << (rel & 31));

            float aw = anchor_w(bn), ah = anchor_h(bn);
            ax4[t] = make_float4(gx - (float)gi, gy - (float)gj,
                                 logf(fmaxf(gw, 1e-12f) / aw),
                                 logf(fmaxf(gh, 1e-12f) / ah));
            scls[t] = min(max((int)tb0, 0), NCLS - 1);
        } else if (t < NTPAD) {
            // finite dummies: wc <= -2e18 (always negative); gwgh = 4e36 (finite, no NaN)
            corners[t] = make_float4(-1e18f, 1e18f, -1e18f, 1e18f);
            ((float*)sgwgh4)[t] = 4e36f;
        }

        // ownership masks for this block's up-to-2 target slots (wave-uniform ballots)
        #pragma unroll
        for (int s = 0; s < 2; ++s) {
            int tS = bx + 34 * s;                           // covers 0..67 >= NT
            unsigned long long mm = 0ull;
            if (tS < cnt) {
                int keyO = __shfl(key, tS);
                mm = __ballot(key == keyO);                 // lanes>=cnt have key=-1
                if ((int)__builtin_ctzll(mm) != tS) mm = 0; // owner = first target w/ key
            }
            if (t == 0) s_mm[s] = mm;
        }
    }
    __syncthreads();
    const int cnt = scnt;
    const int cnt4 = (cnt + 3) & ~3;

    // ---- per-cell noobj conf loss (2 cells per thread) ----
    float acc = 0.0f;
    if (validC) {
        int j = r0 / NWG, i0 = r0 - j * NWG;   // both cells share row j (r0 even, 76 even)
        float fj = (float)j;
        float aw_ = anchor_w(a), ah_ = anchor_h(a);
        #define PREP(K, OX, OY, OW, OH, OC)                                    \
            float px##K = 1.f / (1.f + __expf(-(OX))) + (float)(i0 + K);       \
            float py##K = 1.f / (1.f + __expf(-(OY))) + fj;                    \
            float pw##K = __expf(OW) * aw_;                                    \
            float ph##K = __expf(OH) * ah_;                                    \
            float conf##K = 1.f / (1.f + __expf(-(OC)));                       \
            float xh##K = fmaf(0.5f, pw##K, px##K);                            \
            float xl##K = fmaf(-0.5f, pw##K, px##K);                           \
            float yh##K = fmaf(0.5f, ph##K, py##K);                            \
            float yl##K = fmaf(-0.5f, ph##K, py##K);                           \
            float pwh##K = pw##K * ph##K;
        PREP(0, X.x, Y.x, W.x, H.x, C.x)
        PREP(1, X.y, Y.y, W.y, H.y, C.y)
        #undef PREP

        float B0 = -1e30f, B1 = -1e30f;
        for (int t = 0; t < cnt4; t += 4) {
            float4 e0 = corners[t + 0];
            float4 e1 = corners[t + 1];
            float4 e2 = corners[t + 2];
            float4 e3 = corners[t + 3];
            float4 g  = sgwgh4[t >> 2];
            #define EVT(E, G)                                                  \
                B0 = eval1(xh0, xl0, yh0, yl0, pwh0, E, G, B0);                \
                B1 = eval1(xh1, xl1, yh1, yl1, pwh1, E, G, B1);
            EVT(e0, g.x) EVT(e1, g.y) EVT(e2, g.z) EVT(e3, g.w)
            #undef EVT
        }
        // obj-cell bits for this thread's 2 cells: 2 bits of the bitmap
        unsigned wbits = (obm[tid >> 4] >> ((tid & 15) * 2)) & 0x3u;
        if (!(wbits & 1u) && B0 <= 0.0f) acc += bce_zero(conf0);
        if (!(wbits & 2u) && B1 <= 0.0f) acc += bce_zero(conf1);
    }

    // ---- obj-cell loss: 2 target slots in parallel tid ranges [0,84],[85,169] ----
    {
        int s = tid / 85;
        if (s < 2) {
            unsigned long long mmv = s_mm[s];
            if (mmv != 0ull) {
                int local = tid - s * 85;
                if (local < NCLS) {
                    int keyO = skey[(int)__builtin_ctzll(mmv)];
                    int a2 = keyO / PLANE;
                    const float* base2 = outb + (size_t)a2 * CH_PER_A * PLANE + (keyO - a2 * PLANE);
                    float v = base2[(size_t)(5 + local) * PLANE];
                    bool member = false;
                    unsigned long long mm2 = mmv;
                    while (mm2) {
                        int L = (int)__builtin_ctzll(mm2);
                        mm2 &= mm2 - 1ull;
                        member = member || (scls[L] == local);
                    }
                    acc += softplus_f(v) - (member ? v : 0.f);
                } else if (local == NCLS) {
                    int tlast = 63 - (int)__builtin_clzll(mmv);
                    int keyO = skey[tlast];
                    int a2 = keyO / PLANE;
                    int r2 = keyO - a2 * PLANE;
                    int gj2 = r2 / NWG, gi2 = r2 - gj2 * NWG;
                    const float* base2 = outb + (size_t)a2 * CH_PER_A * PLANE + r2;
                    float o0 = base2[0], o1 = base2[PLANE], o2 = base2[2 * PLANE],
                          o3 = base2[3 * PLANE], o4 = base2[4 * PLANE];
                    float4 cn = corners[tlast];
                    float4 e  = ax4[tlast];
                    float aw = anchor_w(a2), ah = anchor_h(a2);
                    float sx = 1.f / (1.f + expf(-o0));
                    float sy = 1.f / (1.f + expf(-o1));
                    float conf = 1.f / (1.f + expf(-o4));
                    float px = sx + (float)gi2, py = sy + (float)gj2;
                    float pw = expf(o2) * aw, ph = expf(o3) * ah;
                    // iou_cc(gt, pred) via gt corners (bit-equal construction)
                    float gw_ = cn.x - cn.y, gh_ = cn.z - cn.w;
                    float wu = fmaxf(cn.x, px + pw * 0.5f) - fminf(cn.y, px - pw * 0.5f);
                    float hu = fmaxf(cn.z, py + ph * 0.5f) - fminf(cn.w, py - ph * 0.5f);
                    float wc = (gw_ + pw) - wu;
                    float hc = (gh_ + ph) - hu;
                    float inter = (wc <= 0.f || hc <= 0.f) ? 0.f : wc * hc;
                    float uni = gw_ * gh_ + pw * ph - inter;
                    float iou = inter / uni;
                    float dw = o2 - e.z, dh = o3 - e.w;
                    acc += safe_bce_f(sx, e.x) + safe_bce_f(sy, e.y)
                         + dw * dw + dh * dh + safe_bce_f(conf, iou);
                }
            }
        }
    }

    // ---- block reduce -> publish packed {TOKEN, bits} ----
    for (int off = 32; off > 0; off >>= 1) acc += __shfl_down(acc, off);
    int lane = tid & 63, wid = tid >> 6;
    if (lane == 0) partial[wid] = acc;
    __syncthreads();

    const int id = b * BLK_X + bx;
    if (tid == 0) {
        float blocksum = partial[0] + partial[1] + partial[2] + partial[3];
        unsigned long long v = ((unsigned long long)TOKEN << 32)
                             | (unsigned long long)__float_as_uint(blocksum);
        __hip_atomic_store(&slots[id], v, __ATOMIC_RELEASE, __HIP_MEMORY_SCOPE_AGENT);
    }

    // ---- last block: spin-gather all partials, reduce, write d_out ----
    if (id == NPART - 1) {
        __syncthreads();   // ensure tid0's partial[] reads done before reuse below
        float aa = 0.0f;
        for (int k = tid; k < NPART; k += 256) {
            unsigned long long v;
            for (;;) {
                v = __hip_atomic_load(&slots[k], __ATOMIC_ACQUIRE, __HIP_MEMORY_SCOPE_AGENT);
                if ((unsigned)(v >> 32) == TOKEN) break;
                __builtin_amdgcn_s_sleep(1);
            }
            aa += __uint_as_float((unsigned)v);
        }
        for (int off = 32; off > 0; off >>= 1) aa += __shfl_down(aa, off);
        if (lane == 0) partial[wid] = aa;
        __syncthreads();
        if (tid == 0)
            d_out[0] = (partial[0] + partial[1] + partial[2] + partial[3])
                     * (1.0f / (float)NBATCH);
    }
}

extern "C" void kernel_launch(void* const* d_in, const int* in_sizes, int n_in,
                              void* d_out, int out_size, void* d_ws, size_t ws_size,
                              hipStream_t stream) {
    (void)in_sizes; (void)n_in; (void)out_size; (void)ws_size;
    const float* out = (const float*)d_in[0];
    const float* tgt = (const float*)d_in[1];
    unsigned long long* slots = (unsigned long long*)d_ws;

    dim3 grid(BLK_X, NBATCH);
    hipLaunchKernelGGL(yolo_fused, grid, dim3(256), 0, stream, out, tgt, slots, (float*)d_out);
}

// Round 6
// 14.792 us; speedup vs baseline: 1.0454x; 1.0454x over previous
//
#include <hip/hip_runtime.h>
#include <cstdint>
#include <cstddef>

#define NWG 76
#define NHG 76
#define NAC 3
#define NCLS 80
#define NT 50
#define NTPAD 52
#define NBATCH 16
#define PLANE 5776                   // 76*76
#define CELLS_PER_B 17328            // 3*PLANE
#define CH_PER_A 85
#define CH_TOTAL 255
#define CHUNKS_PER_B 4332            // 17328/4, each chunk = 4 consecutive cells
#define BLK_X 17                     // ceil(4332/256)
#define NPART (BLK_X * NBATCH)       // 272
#define TOKEN 0x5A5A5A5Au

__device__ __forceinline__ float anchor_w(int n) { return n == 0 ? 10.f : n == 1 ? 16.f : 33.f; }
__device__ __forceinline__ float anchor_h(int n) { return n == 0 ? 13.f : n == 1 ? 30.f : 23.f; }

__device__ __forceinline__ float safe_bce_f(float p, float t) {
    float lp = (p > 0.0f) ? fmaxf(__logf(fmaxf(p, 1e-38f)), -100.0f) : -100.0f;
    float ln = (p < 1.0f) ? fmaxf(__logf(fmaxf(1.0f - p, 1e-38f)), -100.0f) : -100.0f;
    return -(t * lp + (1.0f - t) * ln);
}
__device__ __forceinline__ float bce_zero(float p) {   // safe_bce(p, 0)
    float ln = (p < 1.0f) ? fmaxf(__logf(fmaxf(1.0f - p, 1e-38f)), -100.0f) : -100.0f;
    return -ln;
}
__device__ __forceinline__ float softplus_f(float x) {
    return (x > 20.0f) ? x : log1pf(__expf(x));
}
// precise replication of reference iou_cc (rare paths only)
__device__ __forceinline__ float iou_cc_f(float x1, float y1, float w1, float h1,
                                          float x2, float y2, float w2, float h2) {
    float wu = fmaxf(x1 + w1 * 0.5f, x2 + w2 * 0.5f) - fminf(x1 - w1 * 0.5f, x2 - w2 * 0.5f);
    float hu = fmaxf(y1 + h1 * 0.5f, y2 + h2 * 0.5f) - fminf(y1 - h1 * 0.5f, y2 - h2 * 0.5f);
    float wc = w1 + w2 - wu;
    float hc = h1 + h2 - hu;
    float inter = (wc <= 0.0f || hc <= 0.0f) ? 0.0f : wc * hc;
    float uni = w1 * h1 + w2 * h2 - inter;
    return inter / uni;
}

// screen: covered <=> wc>0 && hc>0 && 3*inter > den  <=>  min3(wc,hc,3*wc*hc-den) > 0
__device__ __forceinline__ float eval1(float xh, float xl, float yh, float yl,
                                       float pwh, float4 E, float G, float B) {
    float wc = fminf(xh, E.x) - fmaxf(xl, E.y);
    float hc = fminf(yh, E.z) - fmaxf(yl, E.w);
    float t3 = fmaf(3.0f, wc * hc, -(pwh + G));
    return fmaxf(B, fminf(fminf(wc, hc), t3));
}

__global__ void __launch_bounds__(256) yolo_fused(const float* __restrict__ out,
                                                  const float* __restrict__ tgt,
                                                  unsigned long long* __restrict__ slots,
                                                  float* __restrict__ d_out) {
    __shared__ float4 corners[NTPAD];          // {gxh, gxl, gyh, gyl}; dummies kill inter
    __shared__ float4 sgwgh4[NTPAD / 4];       // per-target gw_*gh_ (SoA, broadcast b128)
    __shared__ float4 ax4[NT];                 // {tx, ty, tw, th}
    __shared__ int    skey[NT];                // cell key per target
    __shared__ int    scls[NT];                // class id per target
    __shared__ unsigned obm[32];               // obj-cell bitmap for this block's 1024 cells
    __shared__ unsigned long long s_mm[3];     // ownership masks for target slots bx+17s
    __shared__ float partial[4];
    __shared__ int scnt;

    const int b = blockIdx.y, bx = blockIdx.x, tid = threadIdx.x;
    const float* outb = out + (size_t)b * CH_TOTAL * PLANE;
    const int blockStart = bx * 1024;          // first CELL of this block

    // ---- issue this thread's 4-cell vector loads FIRST (latency hides under build) ----
    const int chunk = bx * 256 + tid;
    const bool validC = (chunk < CHUNKS_PER_B);
    const int cc = validC ? chunk : 0;
    const int cell0 = cc * 4;                  // 4 consecutive cells, same anchor, same row
    const int a = cell0 / PLANE;
    const int r0 = cell0 - a * PLANE;          // r0 % 4 == 0  -> 16B-aligned float4 loads
    const float* base = outb + (size_t)a * CH_PER_A * PLANE + r0;
    float4 X = *reinterpret_cast<const float4*>(base);
    float4 Y = *reinterpret_cast<const float4*>(base + PLANE);
    float4 W = *reinterpret_cast<const float4*>(base + 2 * PLANE);
    float4 H = *reinterpret_cast<const float4*>(base + 3 * PLANE);
    float4 C = *reinterpret_cast<const float4*>(base + 4 * PLANE);

    // ---- wave 0: build GT tables (tgt-only; NO out[] reads) ----
    if (tid < 64) {
        int t = tid;
        if (t < 32) obm[t] = 0u;

        float tb0 = 0.f, tb1 = 0.f, tb2 = 0.f, tb3 = 0.f, tb4 = 0.f;
        if (t < NT) {
            const float* p = tgt + (size_t)b * NT * 5 + t * 5;
            tb0 = p[0]; tb1 = p[1]; tb2 = p[2]; tb3 = p[3]; tb4 = p[4];
        }
        bool nz = (t < NT) && (tb1 != 0.0f);
        unsigned long long mask = __ballot(nz);
        unsigned long long inv = (~mask) & ((1ull << NT) - 1ull);
        int cnt = inv ? (int)__builtin_ctzll(inv) : NT;
        if (t == 0) scnt = cnt;

        int key = -1;
        if (t < cnt) {
            float gx = tb1 * (float)NWG, gy = tb2 * (float)NHG;
            float gw = tb3 * 608.0f,     gh = tb4 * 608.0f;
            float best = -1.0f; int bn = 0;
            #pragma unroll
            for (int n = 0; n < NAC; ++n) {
                float iou = iou_cc_f(0.f, 0.f, anchor_w(n), anchor_h(n), 0.f, 0.f, gw, gh);
                if (iou > best) { best = iou; bn = n; }
            }
            int gi = min(max((int)gx, 0), NWG - 1);
            int gj = min(max((int)gy, 0), NHG - 1);
            key = (bn * NHG + gj) * NWG + gi;  // == linear cell index within batch

            float xh = fmaf(0.5f, gw, gx), xl = fmaf(-0.5f, gw, gx);
            float yh = fmaf(0.5f, gh, gy), yl = fmaf(-0.5f, gh, gy);
            corners[t] = make_float4(xh, xl, yh, yl);
            ((float*)sgwgh4)[t] = (xh - xl) * (yh - yl);
            skey[t] = key;
            int rel = key - blockStart;
            if (rel >= 0 && rel < 1024)
                atomicOr(&obm[rel >> 5], 1u << (rel & 31));

            float aw = anchor_w(bn), ah = anchor_h(bn);
            ax4[t] = make_float4(gx - (float)gi, gy - (float)gj,
                                 logf(fmaxf(gw, 1e-12f) / aw),
                                 logf(fmaxf(gh, 1e-12f) / ah));
            scls[t] = min(max((int)tb0, 0), NCLS - 1);
        } else if (t < NTPAD) {
            // finite dummies: wc <= -2e18 (always negative); gwgh = 4e36 (finite, no NaN)
            corners[t] = make_float4(-1e18f, 1e18f, -1e18f, 1e18f);
            ((float*)sgwgh4)[t] = 4e36f;
        }

        // ownership masks for this block's up-to-3 target slots (wave-uniform ballots)
        #pragma unroll
        for (int s = 0; s < 3; ++s) {
            int tS = bx + 17 * s;                           // < 51
            unsigned long long mm = 0ull;
            if (tS < cnt) {
                int keyO = __shfl(key, tS);
                mm = __ballot(key == keyO);                 // lanes>=cnt have key=-1
                if ((int)__builtin_ctzll(mm) != tS) mm = 0; // owner = first target w/ key
            }
            if (t == 0) s_mm[s] = mm;
        }
    }
    __syncthreads();
    const int cnt = scnt;
    const int cnt4 = (cnt + 3) & ~3;

    // ---- per-cell noobj conf loss (4 cells per thread) ----
    float acc = 0.0f;
    if (validC) {
        int j = r0 / NWG, i0 = r0 - j * NWG;   // all 4 cells share row j
        float fj = (float)j;
        float aw_ = anchor_w(a), ah_ = anchor_h(a);
        #define PREP(K, OX, OY, OW, OH, OC)                                    \
            float px##K = 1.f / (1.f + __expf(-(OX))) + (float)(i0 + K);       \
            float py##K = 1.f / (1.f + __expf(-(OY))) + fj;                    \
            float pw##K = __expf(OW) * aw_;                                    \
            float ph##K = __expf(OH) * ah_;                                    \
            float conf##K = 1.f / (1.f + __expf(-(OC)));                       \
            float xh##K = fmaf(0.5f, pw##K, px##K);                            \
            float xl##K = fmaf(-0.5f, pw##K, px##K);                           \
            float yh##K = fmaf(0.5f, ph##K, py##K);                            \
            float yl##K = fmaf(-0.5f, ph##K, py##K);                           \
            float pwh##K = pw##K * ph##K;
        PREP(0, X.x, Y.x, W.x, H.x, C.x)
        PREP(1, X.y, Y.y, W.y, H.y, C.y)
        PREP(2, X.z, Y.z, W.z, H.z, C.z)
        PREP(3, X.w, Y.w, W.w, H.w, C.w)
        #undef PREP

        float B0 = -1e30f, B1 = -1e30f, B2 = -1e30f, B3 = -1e30f;
        for (int t = 0; t < cnt4; t += 4) {
            float4 e0 = corners[t + 0];
            float4 e1 = corners[t + 1];
            float4 e2 = corners[t + 2];
            float4 e3 = corners[t + 3];
            float4 g  = sgwgh4[t >> 2];
            #define EVT(E, G)                                                  \
                B0 = eval1(xh0, xl0, yh0, yl0, pwh0, E, G, B0);                \
                B1 = eval1(xh1, xl1, yh1, yl1, pwh1, E, G, B1);                \
                B2 = eval1(xh2, xl2, yh2, yl2, pwh2, E, G, B2);                \
                B3 = eval1(xh3, xl3, yh3, yl3, pwh3, E, G, B3);
            EVT(e0, g.x) EVT(e1, g.y) EVT(e2, g.z) EVT(e3, g.w)
            #undef EVT
        }
        // obj-cell bits for this thread's 4 cells: one nibble of the bitmap
        unsigned wbits = (obm[tid >> 3] >> ((tid & 7) * 4)) & 0xFu;
        if (!(wbits & 1u) && B0 <= 0.0f) acc += bce_zero(conf0);
        if (!(wbits & 2u) && B1 <= 0.0f) acc += bce_zero(conf1);
        if (!(wbits & 4u) && B2 <= 0.0f) acc += bce_zero(conf2);
        if (!(wbits & 8u) && B3 <= 0.0f) acc += bce_zero(conf3);
    }

    // ---- obj-cell loss: 3 target slots in parallel tid ranges [0,84],[85,169],[170,254] ----
    {
        int s = tid / 85;
        if (s < 3) {
            unsigned long long mmv = s_mm[s];
            if (mmv != 0ull) {
                int local = tid - s * 85;
                if (local < NCLS) {
                    int keyO = skey[(int)__builtin_ctzll(mmv)];
                    int a2 = keyO / PLANE;
                    const float* base2 = outb + (size_t)a2 * CH_PER_A * PLANE + (keyO - a2 * PLANE);
                    float v = base2[(size_t)(5 + local) * PLANE];
                    bool member = false;
                    unsigned long long mm2 = mmv;
                    while (mm2) {
                        int L = (int)__builtin_ctzll(mm2);
                        mm2 &= mm2 - 1ull;
                        member = member || (scls[L] == local);
                    }
                    acc += softplus_f(v) - (member ? v : 0.f);
                } else if (local == NCLS) {
                    int tlast = 63 - (int)__builtin_clzll(mmv);
                    int keyO = skey[tlast];
                    int a2 = keyO / PLANE;
                    int r2 = keyO - a2 * PLANE;
                    int gj2 = r2 / NWG, gi2 = r2 - gj2 * NWG;
                    const float* base2 = outb + (size_t)a2 * CH_PER_A * PLANE + r2;
                    float o0 = base2[0], o1 = base2[PLANE], o2 = base2[2 * PLANE],
                          o3 = base2[3 * PLANE], o4 = base2[4 * PLANE];
                    float4 cn = corners[tlast];
                    float4 e  = ax4[tlast];
                    float aw = anchor_w(a2), ah = anchor_h(a2);
                    float sx = 1.f / (1.f + expf(-o0));
                    float sy = 1.f / (1.f + expf(-o1));
                    float conf = 1.f / (1.f + expf(-o4));
                    float px = sx + (float)gi2, py = sy + (float)gj2;
                    float pw = expf(o2) * aw, ph = expf(o3) * ah;
                    // iou_cc(gt, pred) via gt corners (bit-equal construction)
                    float gw_ = cn.x - cn.y, gh_ = cn.z - cn.w;
                    float wu = fmaxf(cn.x, px + pw * 0.5f) - fminf(cn.y, px - pw * 0.5f);
                    float hu = fmaxf(cn.z, py + ph * 0.5f) - fminf(cn.w, py - ph * 0.5f);
                    float wc = (gw_ + pw) - wu;
                    float hc = (gh_ + ph) - hu;
                    float inter = (wc <= 0.f || hc <= 0.f) ? 0.f : wc * hc;
                    float uni = gw_ * gh_ + pw * ph - inter;
                    float iou = inter / uni;
                    float dw = o2 - e.z, dh = o3 - e.w;
                    acc += safe_bce_f(sx, e.x) + safe_bce_f(sy, e.y)
                         + dw * dw + dh * dh + safe_bce_f(conf, iou);
                }
            }
        }
    }

    // ---- block reduce -> publish packed {TOKEN, bits} ----
    for (int off = 32; off > 0; off >>= 1) acc += __shfl_down(acc, off);
    int lane = tid & 63, wid = tid >> 6;
    if (lane == 0) partial[wid] = acc;
    __syncthreads();

    const int id = b * BLK_X + bx;
    if (tid == 0) {
        float blocksum = partial[0] + partial[1] + partial[2] + partial[3];
        unsigned long long v = ((unsigned long long)TOKEN << 32)
                             | (unsigned long long)__float_as_uint(blocksum);
        __hip_atomic_store(&slots[id], v, __ATOMIC_RELEASE, __HIP_MEMORY_SCOPE_AGENT);
    }

    // ---- last block: spin-gather all partials, reduce, write d_out ----
    if (id == NPART - 1) {
        __syncthreads();   // ensure tid0's partial[] reads done before reuse below
        float aa = 0.0f;
        for (int k = tid; k < NPART; k += 256) {
            unsigned long long v;
            for (;;) {
                v = __hip_atomic_load(&slots[k], __ATOMIC_ACQUIRE, __HIP_MEMORY_SCOPE_AGENT);
                if ((unsigned)(v >> 32) == TOKEN) break;
                __builtin_amdgcn_s_sleep(1);
            }
            aa += __uint_as_float((unsigned)v);
        }
        for (int off = 32; off > 0; off >>= 1) aa += __shfl_down(aa, off);
        if (lane == 0) partial[wid] = aa;
        __syncthreads();
        if (tid == 0)
            d_out[0] = (partial[0] + partial[1] + partial[2] + partial[3])
                     * (1.0f / (float)NBATCH);
    }
}

extern "C" void kernel_launch(void* const* d_in, const int* in_sizes, int n_in,
                              void* d_out, int out_size, void* d_ws, size_t ws_size,
                              hipStream_t stream) {
    (void)in_sizes; (void)n_in; (void)out_size; (void)ws_size;
    const float* out = (const float*)d_in[0];
    const float* tgt = (const float*)d_in[1];
    unsigned long long* slots = (unsigned long long*)d_ws;

    dim3 grid(BLK_X, NBATCH);
    hipLaunchKernelGGL(yolo_fused, grid, dim3(256), 0, stream, out, tgt, slots, (float*)d_out);
}